// Round 10
// baseline (129.288 us; speedup 1.0000x reference)
//
#include <hip/hip_runtime.h>
#include <cstddef>

// InfoNCE loss, B=8192, D=128.
// prep: normalize + bf16(sqrt(S)*e) cast + (label u, conf-sign w) + self-dot
// sim:  triangle-symmetric bf16 MFMA E.E^T with NO LDS AND NO BARRIERS.
//       r7-r9 throughput accounting: every LDS-staged variant paid ~1400 cyc
//       per 350-cyc ct-step because __syncthreads drains vmcnt(0) -- including
//       the just-issued col atomics (~500cyc) and the DMA tail -- every phase.
//       Eb is 2 MB = L2-resident; B-fragments are register-prefetched straight
//       from global (the block's 4 waves share the same 4KB/ct set via L1).
//       Atomics are genuinely fire-and-forget. Register law (r1-r9): declared
//       min-occupancy m -> allocator caps at 256/m; wpe(2,4) -> cap 128 >=
//       demand ~112 -> no spill, 4 waves/SIMD.
// fin:  per-row loss from (tot, dif), mean over valid rows

#define DDIM 128
#define SQRT_TS 3.7982825f   // sqrt((1/0.1) * log2(e)); applied to both operands

typedef short s8bf __attribute__((ext_vector_type(8)));   // 8 bf16 (4 VGPRs)
typedef float f32x4 __attribute__((ext_vector_type(4)));

__device__ __forceinline__ unsigned short f2bf(float f) {
    unsigned int u = __float_as_uint(f);
    u += 0x7fffu + ((u >> 16) & 1u);
    return (unsigned short)(u >> 16);
}
__device__ __forceinline__ float bf2f(unsigned short h) {
    return __uint_as_float(((unsigned int)h) << 16);
}

// ---------------- prep: one wave per row ----------------
__global__ __launch_bounds__(256) void prep_kernel(
    const float* __restrict__ emb, const int* __restrict__ labels,
    const float* __restrict__ conf,
    short* __restrict__ Eb,    // bf16(sqrt(S) * e) — the ONLY embedding array
    float2* __restrict__ uc,   // (label +-1, conf-sign w)
    float* __restrict__ sd,    // self-dot of scaled bf16 values (log2 domain)
    float* __restrict__ tot, float* __restrict__ dif, int B)
{
    int wave = threadIdx.x >> 6;
    int lane = threadIdx.x & 63;
    int row  = blockIdx.x * 4 + wave;
    if (row >= B) return;

    float2 x = ((const float2*)(emb + (size_t)row * DDIM))[lane];
    float ss = x.x * x.x + x.y * x.y;
    #pragma unroll
    for (int m = 32; m; m >>= 1) ss += __shfl_xor(ss, m);
    float inv = SQRT_TS / fmaxf(sqrtf(ss), 1e-12f);

    unsigned short eb0 = f2bf(x.x * inv), eb1 = f2bf(x.y * inv);
    *(ushort2*)(Eb + (size_t)row * DDIM + lane * 2) = make_ushort2(eb0, eb1);

    float b0 = bf2f(eb0), b1 = bf2f(eb1);
    float p = b0 * b0 + b1 * b1;
    #pragma unroll
    for (int m = 32; m; m >>= 1) p += __shfl_xor(p, m);

    if (lane == 0) {
        sd[row] = p;
        float l = labels[row] ? 1.0f : -1.0f;
        float c = conf[row];
        float w = (c > 0.0f) ? 1.0f : ((c < 0.0f) ? -1.0f : 0.0f);
        uc[row] = make_float2(l, w);
        tot[row] = 0.0f;
        dif[row] = 0.0f;
    }
}

// ---------------- sim ----------------
// One upper-triangle 128x128 tile-pair (bi<=bj) per 256-thr block; wave w owns
// rows rowBase..rowBase+31 (2 MFMA row-tiles). B-fragments read directly from
// global (L1/L2), one-deep register prefetch (named sets p/q, unrolled 8 cts).
// Per element: bias = fma(w_row, w_col*5e29, -5e29); e = exp2(acc + bias);
// row: rtot += e, rdif += u_col*e (regs, one flush at end).
// col (off-diag only, by symmetry): per-ct 2-step shfl reduce + direct atomics.
#define MFMA16(A, Bf, C) __builtin_amdgcn_mfma_f32_16x16x32_bf16((A), (Bf), (C), 0, 0, 0)

__global__ __launch_bounds__(256) __attribute__((amdgpu_waves_per_eu(2, 4)))
void sim_kernel(
    const short* __restrict__ Eb, const float2* __restrict__ uc,
    float* __restrict__ tot, float* __restrict__ dif, int NT)
{
    const int lane = threadIdx.x & 63;
    const int wave = threadIdx.x >> 6;
    const int l16  = lane & 15;
    const int quad = lane >> 4;

    // triangle decode: bi <= bj, C(i) = i*(M-i)/2, M = 2*NT+1
    const int M = 2 * NT + 1;
    int bid = (int)blockIdx.x;
    int bi = (int)((M - sqrtf((float)(M * M - 8 * bid))) * 0.5f);
    while (bi > 0 && bi * (M - bi) / 2 > bid) --bi;
    while ((bi + 1) * (M - bi - 1) / 2 <= bid) ++bi;
    const int bj = bi + (bid - bi * (M - bi) / 2);
    const bool offdiag = (bi != bj);

    const int rowBase = bi * 128 + wave * 32;   // 2 row-tiles
    const int colBase = bj * 128;

    // A fragments: A[m=l16][k=quad*8+j], contiguous b128 from global
    s8bf a[2][4];
    #pragma unroll
    for (int t = 0; t < 2; ++t)
        #pragma unroll
        for (int k = 0; k < 4; ++k)
            a[t][k] = *(const s8bf*)(Eb + (size_t)(rowBase + t * 16 + l16) * DDIM + k * 32 + quad * 8);

    // row characters; C/D layout: col = lane&15, row = quad*4 + reg
    float ur[2][4], wr[2][4], rtot[2][4], rdif[2][4];
    #pragma unroll
    for (int t = 0; t < 2; ++t)
        #pragma unroll
        for (int r = 0; r < 4; ++r) {
            float2 v = uc[rowBase + t * 16 + quad * 4 + r];
            ur[t][r] = v.x; wr[t][r] = v.y;
            rtot[t][r] = 0.0f; rdif[t][r] = 0.0f;
        }

    // B-fragment loads: row = colBase + ct*16 + l16, same fragment layout as A
    #define LDB(v0, v1, v2, v3, ct) do { \
        const short* _p = Eb + (size_t)(colBase + (ct) * 16 + l16) * DDIM + quad * 8; \
        v0 = *(const s8bf*)(_p +  0); \
        v1 = *(const s8bf*)(_p + 32); \
        v2 = *(const s8bf*)(_p + 64); \
        v3 = *(const s8bf*)(_p + 96); \
    } while (0)

    // one 16-col step: MFMAs + epilogue + (off-diag) col reduce/atomics
    #define CT(v0, v1, v2, v3, ct) do { \
        float2 cj = uc[colBase + (ct) * 16 + l16]; \
        float cby = cj.y * 5e29f; \
        f32x4 acc0 = {0.f,0.f,0.f,0.f}, acc1 = {0.f,0.f,0.f,0.f}; \
        acc0 = MFMA16(a[0][0], v0, acc0); \
        acc0 = MFMA16(a[0][1], v1, acc0); \
        acc0 = MFMA16(a[0][2], v2, acc0); \
        acc0 = MFMA16(a[0][3], v3, acc0); \
        acc1 = MFMA16(a[1][0], v0, acc1); \
        acc1 = MFMA16(a[1][1], v1, acc1); \
        acc1 = MFMA16(a[1][2], v2, acc1); \
        acc1 = MFMA16(a[1][3], v3, acc1); \
        float ctA = 0.0f, cdA = 0.0f; \
        _Pragma("unroll") for (int r = 0; r < 4; ++r) { \
            float bias = fmaf(wr[0][r], cby, -5e29f); \
            float e = __builtin_amdgcn_exp2f(acc0[r] + bias); \
            rtot[0][r] += e; rdif[0][r] = fmaf(cj.x, e, rdif[0][r]); \
            ctA += e;        cdA = fmaf(ur[0][r], e, cdA); } \
        _Pragma("unroll") for (int r = 0; r < 4; ++r) { \
            float bias = fmaf(wr[1][r], cby, -5e29f); \
            float e = __builtin_amdgcn_exp2f(acc1[r] + bias); \
            rtot[1][r] += e; rdif[1][r] = fmaf(cj.x, e, rdif[1][r]); \
            ctA += e;        cdA = fmaf(ur[1][r], e, cdA); } \
        if (offdiag) { \
            ctA += __shfl_xor(ctA, 16); cdA += __shfl_xor(cdA, 16); \
            ctA += __shfl_xor(ctA, 32); cdA += __shfl_xor(cdA, 32); \
            if (quad == 0) { \
                atomicAdd(&tot[colBase + (ct) * 16 + l16], ctA); \
                atomicAdd(&dif[colBase + (ct) * 16 + l16], cdA); \
            } \
        } \
    } while (0)

    // software-pipelined 8 ct-steps, two named prefetch sets (no arrays: rule #20)
    s8bf p0, p1, p2, p3, q0, q1, q2, q3;
    LDB(p0, p1, p2, p3, 0);
    LDB(q0, q1, q2, q3, 1); CT(p0, p1, p2, p3, 0);
    LDB(p0, p1, p2, p3, 2); CT(q0, q1, q2, q3, 1);
    LDB(q0, q1, q2, q3, 3); CT(p0, p1, p2, p3, 2);
    LDB(p0, p1, p2, p3, 4); CT(q0, q1, q2, q3, 3);
    LDB(q0, q1, q2, q3, 5); CT(p0, p1, p2, p3, 4);
    LDB(p0, p1, p2, p3, 6); CT(q0, q1, q2, q3, 5);
    LDB(q0, q1, q2, q3, 7); CT(p0, p1, p2, p3, 6);
    CT(q0, q1, q2, q3, 7);

    // ---- row-side flush: reduce over the 16 column-lanes, atomics per row ----
    #pragma unroll
    for (int t = 0; t < 2; ++t)
        #pragma unroll
        for (int r = 0; r < 4; ++r) {
            float tv = rtot[t][r], dv = rdif[t][r];
            tv += __shfl_xor(tv, 1); dv += __shfl_xor(dv, 1);
            tv += __shfl_xor(tv, 2); dv += __shfl_xor(dv, 2);
            tv += __shfl_xor(tv, 4); dv += __shfl_xor(dv, 4);
            tv += __shfl_xor(tv, 8); dv += __shfl_xor(dv, 8);
            if (l16 == 0) {
                int row = rowBase + t * 16 + quad * 4 + r;
                atomicAdd(&tot[row], tv);
                atomicAdd(&dif[row], dv);
            }
        }
}

// ---------------- fin ----------------
__global__ __launch_bounds__(1024) void fin_kernel(
    const float* __restrict__ tot, const float* __restrict__ dif,
    const float* __restrict__ sd, const float2* __restrict__ uc,
    float* __restrict__ out, int B)
{
    __shared__ float ssum[16], scnt[16];
    float sum = 0.0f, cnt = 0.0f;
    for (int i = threadIdx.x; i < B; i += 1024) {
        float u = uc[i].x;
        float P = tot[i];
        float Q = u * dif[i];
        // pos (excl. diag) = (P+Q)/2 - exp2(sd); invalid rows have P=Q=0 -> skipped
        float pos = 0.5f * (P + Q) - __builtin_amdgcn_exp2f(sd[i]);
        float neg = 0.5f * (P - Q);
        if (pos > 0.0f && neg > 0.0f) {
            sum += logf((pos + neg + 1e-8f) / pos);
            cnt += 1.0f;
        }
    }
    #pragma unroll
    for (int m = 32; m; m >>= 1) {
        sum += __shfl_xor(sum, m);
        cnt += __shfl_xor(cnt, m);
    }
    int wave = threadIdx.x >> 6, lane = threadIdx.x & 63;
    if (lane == 0) { ssum[wave] = sum; scnt[wave] = cnt; }
    __syncthreads();
    if (threadIdx.x == 0) {
        float S = 0.0f, C = 0.0f;
        #pragma unroll
        for (int w = 0; w < 16; ++w) { S += ssum[w]; C += scnt[w]; }
        out[0] = (C > 0.0f) ? S / fmaxf(C, 1.0f) : 0.0f;
    }
}

extern "C" void kernel_launch(void* const* d_in, const int* in_sizes, int n_in,
                              void* d_out, int out_size, void* d_ws, size_t ws_size,
                              hipStream_t stream) {
    const float* emb    = (const float*)d_in[0];
    const int*   labels = (const int*)d_in[1];
    const float* conf   = (const float*)d_in[2];
    float* out = (float*)d_out;
    int B = in_sizes[1];   // 8192

    char* ws = (char*)d_ws;
    size_t off = 0;
    short*  Eb  = (short*)(ws + off);  off += (size_t)B * DDIM * 2;
    float2* ucp = (float2*)(ws + off); off += (size_t)B * 8;
    float*  sd  = (float*)(ws + off);  off += (size_t)B * 4;
    float*  tot = (float*)(ws + off);  off += (size_t)B * 4;
    float*  dif = (float*)(ws + off);  off += (size_t)B * 4;

    prep_kernel<<<B / 4, 256, 0, stream>>>(emb, labels, conf, Eb, ucp, sd, tot, dif, B);

    int NT = B / 128;                    // 64 tiles per side
    int nblk = NT * (NT + 1) / 2;        // 2080 upper-triangle tile-pairs
    sim_kernel<<<nblk, 256, 0, stream>>>(Eb, ucp, tot, dif, NT);

    fin_kernel<<<1, 1024, 0, stream>>>(tot, dif, sd, ucp, out, B);
}